// Round 1
// baseline (406.641 us; speedup 1.0000x reference)
//
#include <hip/hip_runtime.h>

#define SPACE_TOK 63
#define INV_T 14.285714285714286f          /* 1/0.07 */
#define SA_SCALE 20.609929155556595f       /* log2(e)/0.07 ; also the static max bound */
#define LN2F 0.6931471805599453f

typedef __attribute__((ext_vector_type(8))) short bf16x8;
typedef __attribute__((ext_vector_type(4))) float f32x4;

__device__ inline unsigned short f2bf(float x) {
  union { float f; unsigned int u; } c; c.f = x;
  unsigned int r = c.u + 0x7fffu + ((c.u >> 16) & 1u);
  return (unsigned short)(r >> 16);
}

// ---------------- char CE: one wave per row of 256 logits ----------------
__global__ void __launch_bounds__(256) ce_kernel(const float* __restrict__ logits,
                                                 const int* __restrict__ targets,
                                                 const float* __restrict__ mask,
                                                 float* __restrict__ W) {
  int tid = threadIdx.x;
  int wave = tid >> 6, lane = tid & 63;
  int rbase = blockIdx.x * 32 + wave * 8;
  float aCM = 0.f, aM = 0.f, aC = 0.f;
  for (int rr = 0; rr < 8; ++rr) {
    int row = rbase + rr;
    float4 v = ((const float4*)logits)[row * 64 + lane];
    float e = __expf(v.x) + __expf(v.y) + __expf(v.z) + __expf(v.w);
#pragma unroll
    for (int m = 1; m < 64; m <<= 1) e += __shfl_xor(e, m);
    int t = targets[row];
    int q = t & 3;
    float sel = (q == 0) ? v.x : (q == 1) ? v.y : (q == 2) ? v.z : v.w;
    float xt = __shfl(sel, t >> 2);
    float ce = __logf(e) - xt;
    float m = mask[row];
    if (lane == 0) { aCM += ce * m; aM += m; aC += ce; }
  }
  __shared__ float red[4][3];
  if (lane == 0) { red[wave][0] = aCM; red[wave][1] = aM; red[wave][2] = aC; }
  __syncthreads();
  if (tid == 0) {
    atomicAdd(W + 0, red[0][0] + red[1][0] + red[2][0] + red[3][0]);
    atomicAdd(W + 1, red[0][1] + red[1][1] + red[2][1] + red[3][1]);
    atomicAdd(W + 2, red[0][2] + red[1][2] + red[2][2] + red[3][2]);
  }
}

// ---------------- space-position scan: one block per batch ----------------
__global__ void __launch_bounds__(256) scan_kernel(const int* __restrict__ targets,
                                                   int* __restrict__ n_sp,
                                                   int* __restrict__ sp_pos) {
  int b = blockIdx.x, tid = threadIdx.x;
  __shared__ int sc[256];
  const int* tb = targets + b * 4096;
  int base = tid * 16;
  int cnt = 0;
#pragma unroll
  for (int i = 0; i < 16; ++i) cnt += (tb[base + i] == SPACE_TOK);
  sc[tid] = cnt;
  __syncthreads();
  for (int off = 1; off < 256; off <<= 1) {
    int v = (tid >= off) ? sc[tid - off] : 0;
    __syncthreads();
    sc[tid] += v;
    __syncthreads();
  }
  int k = sc[tid] - cnt;  // exclusive prefix
  for (int i = 0; i < 16; ++i)
    if (tb[base + i] == SPACE_TOK) sp_pos[b * 4096 + (k++)] = base + i;
  if (tid == 255) n_sp[b] = sc[255];
}

// ---------- word span loss: grid (b, k-strided, d-chunk of 64) ----------
__global__ void __launch_bounds__(256) word_kernel(const float* __restrict__ wp,
                                                   const float* __restrict__ cf,
                                                   const int* __restrict__ n_sp,
                                                   const int* __restrict__ sp_pos,
                                                   float* __restrict__ W) {
  int b = blockIdx.x;
  int ns = n_sp[b];
  int wave = threadIdx.x >> 6, lane = threadIdx.x & 63;
  int d0 = blockIdx.z * 64;
  float myacc = 0.f;
  for (int k = 1 + blockIdx.y; k <= ns - 1; k += 32) {
    int t0 = sp_pos[b * 4096 + k - 1];   // k-th space (0-based array)
    int t1 = sp_pos[b * 4096 + k];       // (k+1)-th space
    int cnt = t1 - t0 - 1;
    if (cnt <= 0) continue;
    if (blockIdx.z == 0 && threadIdx.x == 0) atomicAdd(W + 4, 1.0f);
    int wpos = t0 >> 1;                  // pos//2, always < 2048
    float invc = 1.0f / (float)cnt;
    for (int dd = 0; dd < 16; ++dd) {
      int d = d0 + wave * 16 + dd;
      const float* row = cf + ((size_t)(b * 512 + d)) * 4096;
      float s = 0.f;
      for (int t = t0 + 1 + lane; t < t1; t += 64) s += row[t];
#pragma unroll
      for (int m = 1; m < 64; m <<= 1) s += __shfl_xor(s, m);
      float mean = s * invc;
      float pred = wp[((size_t)(b * 512 + d)) * 2048 + wpos];
      float diff = pred - mean;
      if (lane == 0) myacc += diff * diff;
    }
  }
  __shared__ float wacc[4];
  if (lane == 0) wacc[wave] = myacc;
  __syncthreads();
  if (threadIdx.x == 0) {
    float t = (wacc[0] + wacc[1] + wacc[2] + wacc[3]) * (1.0f / 512.0f);
    atomicAdd(W + 3, t);
  }
}

// ------- normalize + transpose + bf16 (A side pre-scaled by log2e/T) -------
__global__ void __launch_bounds__(256) norm_kernel(const float* __restrict__ emb, int L,
                                                   unsigned short* __restrict__ Abf,
                                                   unsigned short* __restrict__ Pbf) {
  __shared__ float tile[128][65];
  __shared__ float np4[4][64];
  __shared__ float scl[64];
  int b = blockIdx.x;
  int l0 = blockIdx.y * 64;
  int tid = threadIdx.x;
  int lx = tid & 63, cq = tid >> 6;
  const float* eb = emb + (size_t)b * 128 * L + l0;
  for (int c = cq; c < 128; c += 4) tile[c][lx] = eb[(size_t)c * L + lx];
  __syncthreads();
  {
    float s = 0.f;
    for (int c = cq; c < 128; c += 4) { float x = tile[c][lx]; s += x * x; }
    np4[cq][lx] = s;
  }
  __syncthreads();
  if (tid < 64) {
    float t = np4[0][tid] + np4[1][tid] + np4[2][tid] + np4[3][tid];
    float nrm = fmaxf(sqrtf(t), 1e-12f);
    scl[tid] = ((tid & 1) ? 1.0f : SA_SCALE) / nrm;  // even l -> anchor (scaled)
  }
  __syncthreads();
  int c = tid & 127, lh = tid >> 7;
  int half = L >> 1;
  for (int lp = lh; lp < 64; lp += 2) {
    int l = l0 + lp;
    int row = b * half + (l >> 1);
    unsigned short v = f2bf(tile[c][lp] * scl[lp]);
    ((l & 1) ? Pbf : Abf)[(size_t)row * 128 + c] = v;
  }
}

// ------- InfoNCE: MFMA bf16, static-max streaming softmax denominator -------
__global__ void __launch_bounds__(512) nce_kernel(const unsigned short* __restrict__ A,
                                                  const unsigned short* __restrict__ P,
                                                  int n, float* __restrict__ acc) {
  int tid = threadIdx.x;
  int wave = tid >> 6, lane = tid & 63;
  int col = lane & 15, quad = lane >> 4;
  int I0 = blockIdx.x * 16;
  const unsigned short* Ap = A + (size_t)(I0 + col) * 128 + quad * 8;
  bf16x8 a0 = *(const bf16x8*)(Ap);
  bf16x8 a1 = *(const bf16x8*)(Ap + 32);
  bf16x8 a2 = *(const bf16x8*)(Ap + 64);
  bf16x8 a3 = *(const bf16x8*)(Ap + 96);
  float rl0 = 0.f, rl1 = 0.f, rl2 = 0.f, rl3 = 0.f;
  float dcap = 0.f;
  int Jq = n >> 3;
  int J0w = wave * Jq, Jend = J0w + Jq;
#pragma unroll 2
  for (int J = J0w; J < Jend; J += 16) {
    const unsigned short* Pp = P + (size_t)(J + col) * 128 + quad * 8;
    bf16x8 b0 = *(const bf16x8*)(Pp);
    bf16x8 b1 = *(const bf16x8*)(Pp + 32);
    bf16x8 b2 = *(const bf16x8*)(Pp + 64);
    bf16x8 b3 = *(const bf16x8*)(Pp + 96);
    f32x4 cfr = {0.f, 0.f, 0.f, 0.f};
    cfr = __builtin_amdgcn_mfma_f32_16x16x32_bf16(a0, b0, cfr, 0, 0, 0);
    cfr = __builtin_amdgcn_mfma_f32_16x16x32_bf16(a1, b1, cfr, 0, 0, 0);
    cfr = __builtin_amdgcn_mfma_f32_16x16x32_bf16(a2, b2, cfr, 0, 0, 0);
    cfr = __builtin_amdgcn_mfma_f32_16x16x32_bf16(a3, b3, cfr, 0, 0, 0);
    rl0 += exp2f(cfr[0] - SA_SCALE);
    rl1 += exp2f(cfr[1] - SA_SCALE);
    rl2 += exp2f(cfr[2] - SA_SCALE);
    rl3 += exp2f(cfr[3] - SA_SCALE);
    if (J == I0) {                        // diagonal tile
      int r = col - (quad << 2);
      if (r == 0) dcap = cfr[0];
      else if (r == 1) dcap = cfr[1];
      else if (r == 2) dcap = cfr[2];
      else if (r == 3) dcap = cfr[3];
    }
  }
  __shared__ float part[8][16][16];
  __shared__ float dpart[8][16];
  __shared__ float rowc[16];
  part[wave][(quad << 2) + 0][col] = rl0;
  part[wave][(quad << 2) + 1][col] = rl1;
  part[wave][(quad << 2) + 2][col] = rl2;
  part[wave][(quad << 2) + 3][col] = rl3;
  if (quad == (col >> 2)) dpart[wave][col] = dcap;
  __syncthreads();
  if (tid < 256) {
    int rrow = tid >> 4, cc = tid & 15;
    float s = 0.f, d = 0.f;
#pragma unroll
    for (int w = 0; w < 8; ++w) { s += part[w][rrow][cc]; d += dpart[w][rrow]; }
#pragma unroll
    for (int m = 1; m < 16; m <<= 1) s += __shfl_xor(s, m);
    // per-row: logsumexp - s_ii = 1/T + ln(sum_exp2(c - M)) - ln2 * c_ii
    if (cc == 0) rowc[rrow] = INV_T + __logf(s) - LN2F * d;
  }
  __syncthreads();
  if (tid == 0) {
    float t = 0.f;
#pragma unroll
    for (int i = 0; i < 16; ++i) t += rowc[i];
    atomicAdd(acc, t);
  }
}

// ---------------- final combine ----------------
__global__ void final_kernel(const float* __restrict__ W, float* __restrict__ out) {
  float n = W[1];
  float charL = (n > 0.f) ? (W[0] / fmaxf(n, 1.f)) : (W[2] / 32768.0f);
  float cnt = W[4];
  float wordL = (cnt > 0.f) ? (W[3] / fmaxf(cnt, 1.f)) : 0.f;
  float phrase = W[5] / 4096.0f;
  float idea = W[6] / 1024.0f;
  out[0] = charL + 0.5f * wordL + 0.1f * phrase + 0.1f * idea;
}

extern "C" void kernel_launch(void* const* d_in, const int* in_sizes, int n_in,
                              void* d_out, int out_size, void* d_ws, size_t ws_size,
                              hipStream_t stream) {
  (void)in_sizes; (void)n_in; (void)out_size; (void)ws_size;
  const float* logits        = (const float*)d_in[0];
  const float* word_preds    = (const float*)d_in[1];
  const float* char_features = (const float*)d_in[2];
  const float* c2            = (const float*)d_in[3];
  const float* c3            = (const float*)d_in[4];
  const int*   targets       = (const int*)d_in[5];
  const float* mask          = (const float*)d_in[6];
  float* out = (float*)d_out;

  char* ws = (char*)d_ws;
  float* W    = (float*)ws;              // W[0..6] accumulators
  int* n_sp   = (int*)(ws + 64);         // 8 ints
  int* sp_pos = (int*)(ws + 128);        // 8*4096 ints, ends at 131200
  unsigned short* A2 = (unsigned short*)(ws + 131200);  // 4096*128 bf16
  unsigned short* P2 = A2 + 4096 * 128;
  unsigned short* A3 = P2 + 4096 * 128;  // 1024*128 bf16
  unsigned short* P3 = A3 + 1024 * 128;  // total ws use ~2.75 MB

  hipMemsetAsync(d_ws, 0, 64, stream);
  scan_kernel<<<8, 256, 0, stream>>>(targets, n_sp, sp_pos);
  ce_kernel<<<1024, 256, 0, stream>>>(logits, targets, mask, W);
  word_kernel<<<dim3(8, 32, 8), 256, 0, stream>>>(word_preds, char_features, n_sp, sp_pos, W);
  norm_kernel<<<dim3(8, 16), 256, 0, stream>>>(c2, 1024, A2, P2);
  norm_kernel<<<dim3(8, 4), 256, 0, stream>>>(c3, 256, A3, P3);
  nce_kernel<<<256, 512, 0, stream>>>(A2, P2, 4096, W + 5);
  nce_kernel<<<64, 512, 0, stream>>>(A3, P3, 1024, W + 6);
  final_kernel<<<1, 1, 0, stream>>>(W, out);
}

// Round 2
// 307.528 us; speedup vs baseline: 1.3223x; 1.3223x over previous
//
#include <hip/hip_runtime.h>

#define SPACE_TOK 63
#define INV_T 14.285714285714286f          /* 1/0.07 */
#define SA_SCALE 20.609929155556595f       /* log2(e)/0.07 ; also the static max bound */
#define LN2F 0.6931471805599453f

typedef __attribute__((ext_vector_type(8))) short bf16x8;
typedef __attribute__((ext_vector_type(4))) float f32x4;

__device__ inline unsigned short f2bf(float x) {
  union { float f; unsigned int u; } c; c.f = x;
  unsigned int r = c.u + 0x7fffu + ((c.u >> 16) & 1u);
  return (unsigned short)(r >> 16);
}

// ---------------- char CE: one wave per row of 256 logits ----------------
// R1: preload all 8 rows (8 independent 16B loads in flight) before reducing.
__global__ void __launch_bounds__(256) ce_kernel(const float* __restrict__ logits,
                                                 const int* __restrict__ targets,
                                                 const float* __restrict__ mask,
                                                 float* __restrict__ W) {
  int tid = threadIdx.x;
  int wave = tid >> 6, lane = tid & 63;
  int rbase = blockIdx.x * 32 + wave * 8;
  float4 v[8];
  float mk[8];
  int tg[8];
#pragma unroll
  for (int rr = 0; rr < 8; ++rr) v[rr] = ((const float4*)logits)[(size_t)(rbase + rr) * 64 + lane];
#pragma unroll
  for (int rr = 0; rr < 8; ++rr) { tg[rr] = targets[rbase + rr]; mk[rr] = mask[rbase + rr]; }
  float aCM = 0.f, aM = 0.f, aC = 0.f;
#pragma unroll
  for (int rr = 0; rr < 8; ++rr) {
    float e = __expf(v[rr].x) + __expf(v[rr].y) + __expf(v[rr].z) + __expf(v[rr].w);
#pragma unroll
    for (int m = 1; m < 64; m <<= 1) e += __shfl_xor(e, m);
    int t = tg[rr];
    int q = t & 3;
    float sel = (q == 0) ? v[rr].x : (q == 1) ? v[rr].y : (q == 2) ? v[rr].z : v[rr].w;
    float xt = __shfl(sel, t >> 2);
    float ce = __logf(e) - xt;
    aCM += ce * mk[rr]; aM += mk[rr]; aC += ce;
  }
  __shared__ float red[4][3];
  if (lane == 0) { red[wave][0] = aCM; red[wave][1] = aM; red[wave][2] = aC; }
  __syncthreads();
  if (tid == 0) {
    atomicAdd(W + 0, red[0][0] + red[1][0] + red[2][0] + red[3][0]);
    atomicAdd(W + 1, red[0][1] + red[1][1] + red[2][1] + red[3][1]);
    atomicAdd(W + 2, red[0][2] + red[1][2] + red[2][2] + red[3][2]);
  }
}

// ---------------- space-position scan: one block per batch ----------------
__global__ void __launch_bounds__(256) scan_kernel(const int* __restrict__ targets,
                                                   int* __restrict__ n_sp,
                                                   int* __restrict__ sp_pos) {
  int b = blockIdx.x, tid = threadIdx.x;
  __shared__ int sc[256];
  const int* tb = targets + b * 4096;
  int base = tid * 16;
  int cnt = 0;
#pragma unroll
  for (int i = 0; i < 16; ++i) cnt += (tb[base + i] == SPACE_TOK);
  sc[tid] = cnt;
  __syncthreads();
  for (int off = 1; off < 256; off <<= 1) {
    int v = (tid >= off) ? sc[tid - off] : 0;
    __syncthreads();
    sc[tid] += v;
    __syncthreads();
  }
  int k = sc[tid] - cnt;  // exclusive prefix
  for (int i = 0; i < 16; ++i)
    if (tb[base + i] == SPACE_TOK) sp_pos[b * 4096 + (k++)] = base + i;
  if (tid == 255) n_sp[b] = sc[255];
}

// ---------- word span loss: grid (b, k-strided, d-chunk of 32) ----------
// R1: 8-way d-interleave per wave (8 independent load/acc chains) + z=16.
__global__ void __launch_bounds__(256) word_kernel(const float* __restrict__ wp,
                                                   const float* __restrict__ cf,
                                                   const int* __restrict__ n_sp,
                                                   const int* __restrict__ sp_pos,
                                                   float* __restrict__ W) {
  int b = blockIdx.x;
  int ns = n_sp[b];
  int wave = threadIdx.x >> 6, lane = threadIdx.x & 63;
  int dbase = blockIdx.z * 32 + wave * 8;   // this wave's 8 d-rows
  float myacc = 0.f;                         // live on lanes 0..7
  for (int k = 1 + blockIdx.y; k <= ns - 1; k += 32) {
    int t0 = sp_pos[b * 4096 + k - 1];
    int t1 = sp_pos[b * 4096 + k];
    int cnt = t1 - t0 - 1;
    if (cnt <= 0) continue;
    if (blockIdx.z == 0 && threadIdx.x == 0) atomicAdd(W + 4, 1.0f);
    int wpos = t0 >> 1;                      // pos//2, always < 2048
    float invc = 1.0f / (float)cnt;
    const float* r0 = cf + ((size_t)(b * 512 + dbase)) * 4096;
    float s0 = 0.f, s1 = 0.f, s2 = 0.f, s3 = 0.f, s4 = 0.f, s5 = 0.f, s6 = 0.f, s7 = 0.f;
    for (int t = t0 + 1 + lane; t < t1; t += 64) {
      s0 += r0[t];
      s1 += r0[t + 1 * 4096];
      s2 += r0[t + 2 * 4096];
      s3 += r0[t + 3 * 4096];
      s4 += r0[t + 4 * 4096];
      s5 += r0[t + 5 * 4096];
      s6 += r0[t + 6 * 4096];
      s7 += r0[t + 7 * 4096];
    }
#pragma unroll
    for (int m = 1; m < 64; m <<= 1) {
      s0 += __shfl_xor(s0, m); s1 += __shfl_xor(s1, m);
      s2 += __shfl_xor(s2, m); s3 += __shfl_xor(s3, m);
      s4 += __shfl_xor(s4, m); s5 += __shfl_xor(s5, m);
      s6 += __shfl_xor(s6, m); s7 += __shfl_xor(s7, m);
    }
    if (lane < 8) {
      float sv = (lane == 0) ? s0 : (lane == 1) ? s1 : (lane == 2) ? s2 : (lane == 3) ? s3
               : (lane == 4) ? s4 : (lane == 5) ? s5 : (lane == 6) ? s6 : s7;
      float mean = sv * invc;
      float pred = wp[((size_t)(b * 512 + dbase + lane)) * 2048 + wpos];
      float diff = pred - mean;
      myacc += diff * diff;
    }
  }
  // reduce lanes 0..7 -> lane 0
#pragma unroll
  for (int m = 1; m < 8; m <<= 1) myacc += __shfl_xor(myacc, m);
  __shared__ float wacc[4];
  if (lane == 0) wacc[wave] = myacc;
  __syncthreads();
  if (threadIdx.x == 0) {
    float t = (wacc[0] + wacc[1] + wacc[2] + wacc[3]) * (1.0f / 512.0f);
    atomicAdd(W + 3, t);
  }
}

// ------- normalize + transpose + bf16 (A side pre-scaled by log2e/T) -------
__global__ void __launch_bounds__(256) norm_kernel(const float* __restrict__ emb, int L,
                                                   unsigned short* __restrict__ Abf,
                                                   unsigned short* __restrict__ Pbf) {
  __shared__ float tile[128][65];
  __shared__ float np4[4][64];
  __shared__ float scl[64];
  int b = blockIdx.x;
  int l0 = blockIdx.y * 64;
  int tid = threadIdx.x;
  int lx = tid & 63, cq = tid >> 6;
  const float* eb = emb + (size_t)b * 128 * L + l0;
  for (int c = cq; c < 128; c += 4) tile[c][lx] = eb[(size_t)c * L + lx];
  __syncthreads();
  {
    float s = 0.f;
    for (int c = cq; c < 128; c += 4) { float x = tile[c][lx]; s += x * x; }
    np4[cq][lx] = s;
  }
  __syncthreads();
  if (tid < 64) {
    float t = np4[0][tid] + np4[1][tid] + np4[2][tid] + np4[3][tid];
    float nrm = fmaxf(sqrtf(t), 1e-12f);
    scl[tid] = ((tid & 1) ? 1.0f : SA_SCALE) / nrm;  // even l -> anchor (scaled)
  }
  __syncthreads();
  int c = tid & 127, lh = tid >> 7;
  int half = L >> 1;
  for (int lp = lh; lp < 64; lp += 2) {
    int l = l0 + lp;
    int row = b * half + (l >> 1);
    unsigned short v = f2bf(tile[c][lp] * scl[lp]);
    ((l & 1) ? Pbf : Abf)[(size_t)row * 128 + c] = v;
  }
}

// ------- InfoNCE: MFMA bf16, static-max streaming softmax denominator -------
__global__ void __launch_bounds__(512) nce_kernel(const unsigned short* __restrict__ A,
                                                  const unsigned short* __restrict__ P,
                                                  int n, float* __restrict__ acc) {
  int tid = threadIdx.x;
  int wave = tid >> 6, lane = tid & 63;
  int col = lane & 15, quad = lane >> 4;
  int I0 = blockIdx.x * 16;
  const unsigned short* Ap = A + (size_t)(I0 + col) * 128 + quad * 8;
  bf16x8 a0 = *(const bf16x8*)(Ap);
  bf16x8 a1 = *(const bf16x8*)(Ap + 32);
  bf16x8 a2 = *(const bf16x8*)(Ap + 64);
  bf16x8 a3 = *(const bf16x8*)(Ap + 96);
  float rl0 = 0.f, rl1 = 0.f, rl2 = 0.f, rl3 = 0.f;
  float dcap = 0.f;
  int Jq = n >> 3;
  int J0w = wave * Jq, Jend = J0w + Jq;
#pragma unroll 2
  for (int J = J0w; J < Jend; J += 16) {
    const unsigned short* Pp = P + (size_t)(J + col) * 128 + quad * 8;
    bf16x8 b0 = *(const bf16x8*)(Pp);
    bf16x8 b1 = *(const bf16x8*)(Pp + 32);
    bf16x8 b2 = *(const bf16x8*)(Pp + 64);
    bf16x8 b3 = *(const bf16x8*)(Pp + 96);
    f32x4 cfr = {0.f, 0.f, 0.f, 0.f};
    cfr = __builtin_amdgcn_mfma_f32_16x16x32_bf16(a0, b0, cfr, 0, 0, 0);
    cfr = __builtin_amdgcn_mfma_f32_16x16x32_bf16(a1, b1, cfr, 0, 0, 0);
    cfr = __builtin_amdgcn_mfma_f32_16x16x32_bf16(a2, b2, cfr, 0, 0, 0);
    cfr = __builtin_amdgcn_mfma_f32_16x16x32_bf16(a3, b3, cfr, 0, 0, 0);
    rl0 += exp2f(cfr[0] - SA_SCALE);
    rl1 += exp2f(cfr[1] - SA_SCALE);
    rl2 += exp2f(cfr[2] - SA_SCALE);
    rl3 += exp2f(cfr[3] - SA_SCALE);
    if (J == I0) {                        // diagonal tile
      int r = col - (quad << 2);
      if (r == 0) dcap = cfr[0];
      else if (r == 1) dcap = cfr[1];
      else if (r == 2) dcap = cfr[2];
      else if (r == 3) dcap = cfr[3];
    }
  }
  __shared__ float part[8][16][16];
  __shared__ float dpart[8][16];
  __shared__ float rowc[16];
  part[wave][(quad << 2) + 0][col] = rl0;
  part[wave][(quad << 2) + 1][col] = rl1;
  part[wave][(quad << 2) + 2][col] = rl2;
  part[wave][(quad << 2) + 3][col] = rl3;
  if (quad == (col >> 2)) dpart[wave][col] = dcap;
  __syncthreads();
  if (tid < 256) {
    int rrow = tid >> 4, cc = tid & 15;
    float s = 0.f, d = 0.f;
#pragma unroll
    for (int w = 0; w < 8; ++w) { s += part[w][rrow][cc]; d += dpart[w][rrow]; }
#pragma unroll
    for (int m = 1; m < 16; m <<= 1) s += __shfl_xor(s, m);
    // per-row: logsumexp - s_ii = 1/T + ln(sum_exp2(c - M)) - ln2 * c_ii
    if (cc == 0) rowc[rrow] = INV_T + __logf(s) - LN2F * d;
  }
  __syncthreads();
  if (tid == 0) {
    float t = 0.f;
#pragma unroll
    for (int i = 0; i < 16; ++i) t += rowc[i];
    atomicAdd(acc, t);
  }
}

// ---------------- final combine ----------------
__global__ void final_kernel(const float* __restrict__ W, float* __restrict__ out) {
  float n = W[1];
  float charL = (n > 0.f) ? (W[0] / fmaxf(n, 1.f)) : (W[2] / 32768.0f);
  float cnt = W[4];
  float wordL = (cnt > 0.f) ? (W[3] / fmaxf(cnt, 1.f)) : 0.f;
  float phrase = W[5] / 4096.0f;
  float idea = W[6] / 1024.0f;
  out[0] = charL + 0.5f * wordL + 0.1f * phrase + 0.1f * idea;
}

extern "C" void kernel_launch(void* const* d_in, const int* in_sizes, int n_in,
                              void* d_out, int out_size, void* d_ws, size_t ws_size,
                              hipStream_t stream) {
  (void)in_sizes; (void)n_in; (void)out_size; (void)ws_size;
  const float* logits        = (const float*)d_in[0];
  const float* word_preds    = (const float*)d_in[1];
  const float* char_features = (const float*)d_in[2];
  const float* c2            = (const float*)d_in[3];
  const float* c3            = (const float*)d_in[4];
  const int*   targets       = (const int*)d_in[5];
  const float* mask          = (const float*)d_in[6];
  float* out = (float*)d_out;

  char* ws = (char*)d_ws;
  float* W    = (float*)ws;              // W[0..6] accumulators
  int* n_sp   = (int*)(ws + 64);         // 8 ints
  int* sp_pos = (int*)(ws + 128);        // 8*4096 ints, ends at 131200
  unsigned short* A2 = (unsigned short*)(ws + 131200);  // 4096*128 bf16
  unsigned short* P2 = A2 + 4096 * 128;
  unsigned short* A3 = P2 + 4096 * 128;  // 1024*128 bf16
  unsigned short* P3 = A3 + 1024 * 128;  // total ws use ~2.75 MB

  hipMemsetAsync(d_ws, 0, 64, stream);
  scan_kernel<<<8, 256, 0, stream>>>(targets, n_sp, sp_pos);
  ce_kernel<<<1024, 256, 0, stream>>>(logits, targets, mask, W);
  word_kernel<<<dim3(8, 32, 16), 256, 0, stream>>>(word_preds, char_features, n_sp, sp_pos, W);
  norm_kernel<<<dim3(8, 16), 256, 0, stream>>>(c2, 1024, A2, P2);
  norm_kernel<<<dim3(8, 4), 256, 0, stream>>>(c3, 256, A3, P3);
  nce_kernel<<<256, 512, 0, stream>>>(A2, P2, 4096, W + 5);
  nce_kernel<<<64, 512, 0, stream>>>(A3, P3, 1024, W + 6);
  final_kernel<<<1, 1, 0, stream>>>(W, out);
}

// Round 3
// 302.483 us; speedup vs baseline: 1.3443x; 1.0167x over previous
//
#include <hip/hip_runtime.h>

#define SPACE_TOK 63
#define INV_T 14.285714285714286f          /* 1/0.07 */
#define SA_SCALE 20.609929155556595f       /* log2(e)/0.07 ; also the static max bound */
#define LN2F 0.6931471805599453f

typedef __attribute__((ext_vector_type(8))) short bf16x8;
typedef __attribute__((ext_vector_type(4))) float f32x4;

__device__ inline unsigned short f2bf(float x) {
  union { float f; unsigned int u; } c; c.f = x;
  unsigned int r = c.u + 0x7fffu + ((c.u >> 16) & 1u);
  return (unsigned short)(r >> 16);
}

// ---------------- char CE: one wave per row of 256 logits ----------------
__global__ void __launch_bounds__(256) ce_kernel(const float* __restrict__ logits,
                                                 const int* __restrict__ targets,
                                                 const float* __restrict__ mask,
                                                 float* __restrict__ W) {
  int tid = threadIdx.x;
  int wave = tid >> 6, lane = tid & 63;
  int rbase = blockIdx.x * 32 + wave * 8;
  float4 v[8];
  float mk[8];
  int tg[8];
#pragma unroll
  for (int rr = 0; rr < 8; ++rr) v[rr] = ((const float4*)logits)[(size_t)(rbase + rr) * 64 + lane];
#pragma unroll
  for (int rr = 0; rr < 8; ++rr) { tg[rr] = targets[rbase + rr]; mk[rr] = mask[rbase + rr]; }
  float aCM = 0.f, aM = 0.f, aC = 0.f;
#pragma unroll
  for (int rr = 0; rr < 8; ++rr) {
    float e = __expf(v[rr].x) + __expf(v[rr].y) + __expf(v[rr].z) + __expf(v[rr].w);
#pragma unroll
    for (int m = 1; m < 64; m <<= 1) e += __shfl_xor(e, m);
    int t = tg[rr];
    int q = t & 3;
    float sel = (q == 0) ? v[rr].x : (q == 1) ? v[rr].y : (q == 2) ? v[rr].z : v[rr].w;
    float xt = __shfl(sel, t >> 2);
    float ce = __logf(e) - xt;
    aCM += ce * mk[rr]; aM += mk[rr]; aC += ce;
  }
  __shared__ float red[4][3];
  if (lane == 0) { red[wave][0] = aCM; red[wave][1] = aM; red[wave][2] = aC; }
  __syncthreads();
  if (tid == 0) {
    atomicAdd(W + 0, red[0][0] + red[1][0] + red[2][0] + red[3][0]);
    atomicAdd(W + 1, red[0][1] + red[1][1] + red[2][1] + red[3][1]);
    atomicAdd(W + 2, red[0][2] + red[1][2] + red[2][2] + red[3][2]);
  }
}

// ---------------- space-position scan: one block per batch ----------------
// R2: coalesced int4 staging into LDS (old version did stride-64B scalar loads).
__global__ void __launch_bounds__(256) scan_kernel(const int* __restrict__ targets,
                                                   int* __restrict__ n_sp,
                                                   int* __restrict__ sp_pos) {
  int b = blockIdx.x, tid = threadIdx.x;
  __shared__ int toks[4096];
  __shared__ int sc[256];
  const int4* tb4 = (const int4*)(targets + b * 4096);
#pragma unroll
  for (int i = 0; i < 4; ++i) ((int4*)toks)[tid + 256 * i] = tb4[tid + 256 * i];
  __syncthreads();
  int base = tid * 16;
  int cnt = 0;
#pragma unroll
  for (int i = 0; i < 16; ++i) cnt += (toks[base + i] == SPACE_TOK);
  sc[tid] = cnt;
  __syncthreads();
  for (int off = 1; off < 256; off <<= 1) {
    int v = (tid >= off) ? sc[tid - off] : 0;
    __syncthreads();
    sc[tid] += v;
    __syncthreads();
  }
  int k = sc[tid] - cnt;  // exclusive prefix
  for (int i = 0; i < 16; ++i)
    if (toks[base + i] == SPACE_TOK) sp_pos[b * 4096 + (k++)] = base + i;
  if (tid == 255) n_sp[b] = sc[255];
}

// ---------- word span loss: grid (b, k-strided, d-chunk of 32) ----------
// R2: aligned float4 loads + per-component predication; 8 rows in flight.
__global__ void __launch_bounds__(256) word_kernel(const float* __restrict__ wp,
                                                   const float* __restrict__ cf,
                                                   const int* __restrict__ n_sp,
                                                   const int* __restrict__ sp_pos,
                                                   float* __restrict__ W) {
  int b = blockIdx.x;
  int ns = n_sp[b];
  int wave = threadIdx.x >> 6, lane = threadIdx.x & 63;
  int dbase = blockIdx.z * 32 + wave * 8;   // this wave's 8 d-rows
  float myacc = 0.f;
  for (int k = 1 + blockIdx.y; k <= ns - 1; k += 32) {
    int t0 = sp_pos[b * 4096 + k - 1];
    int t1 = sp_pos[b * 4096 + k];
    int cnt = t1 - t0 - 1;
    if (cnt <= 0) continue;
    if (blockIdx.z == 0 && threadIdx.x == 0) atomicAdd(W + 4, 1.0f);
    int wpos = t0 >> 1;                      // pos//2, always < 2048
    float invc = 1.0f / (float)cnt;
    const float* r0 = cf + ((size_t)(b * 512 + dbase)) * 4096;
    int c0 = (t0 + 1) >> 2;                  // first float4 chunk (floor)
    int c1 = (t1 + 3) >> 2;                  // end float4 chunk (ceil)
    float s0 = 0.f, s1 = 0.f, s2 = 0.f, s3 = 0.f, s4 = 0.f, s5 = 0.f, s6 = 0.f, s7 = 0.f;
    for (int c = c0 + lane; c < c1; c += 64) {
      int tb = c << 2;
      float4 v0 = *(const float4*)(r0 + 0 * 4096 + tb);
      float4 v1 = *(const float4*)(r0 + 1 * 4096 + tb);
      float4 v2 = *(const float4*)(r0 + 2 * 4096 + tb);
      float4 v3 = *(const float4*)(r0 + 3 * 4096 + tb);
      float4 v4 = *(const float4*)(r0 + 4 * 4096 + tb);
      float4 v5 = *(const float4*)(r0 + 5 * 4096 + tb);
      float4 v6 = *(const float4*)(r0 + 6 * 4096 + tb);
      float4 v7 = *(const float4*)(r0 + 7 * 4096 + tb);
      float m0 = (tb + 0 > t0 && tb + 0 < t1) ? 1.f : 0.f;
      float m1 = (tb + 1 > t0 && tb + 1 < t1) ? 1.f : 0.f;
      float m2 = (tb + 2 > t0 && tb + 2 < t1) ? 1.f : 0.f;
      float m3 = (tb + 3 > t0 && tb + 3 < t1) ? 1.f : 0.f;
      s0 += v0.x * m0 + v0.y * m1 + v0.z * m2 + v0.w * m3;
      s1 += v1.x * m0 + v1.y * m1 + v1.z * m2 + v1.w * m3;
      s2 += v2.x * m0 + v2.y * m1 + v2.z * m2 + v2.w * m3;
      s3 += v3.x * m0 + v3.y * m1 + v3.z * m2 + v3.w * m3;
      s4 += v4.x * m0 + v4.y * m1 + v4.z * m2 + v4.w * m3;
      s5 += v5.x * m0 + v5.y * m1 + v5.z * m2 + v5.w * m3;
      s6 += v6.x * m0 + v6.y * m1 + v6.z * m2 + v6.w * m3;
      s7 += v7.x * m0 + v7.y * m1 + v7.z * m2 + v7.w * m3;
    }
#pragma unroll
    for (int m = 1; m < 64; m <<= 1) {
      s0 += __shfl_xor(s0, m); s1 += __shfl_xor(s1, m);
      s2 += __shfl_xor(s2, m); s3 += __shfl_xor(s3, m);
      s4 += __shfl_xor(s4, m); s5 += __shfl_xor(s5, m);
      s6 += __shfl_xor(s6, m); s7 += __shfl_xor(s7, m);
    }
    if (lane < 8) {
      float sv = (lane == 0) ? s0 : (lane == 1) ? s1 : (lane == 2) ? s2 : (lane == 3) ? s3
               : (lane == 4) ? s4 : (lane == 5) ? s5 : (lane == 6) ? s6 : s7;
      float mean = sv * invc;
      float pred = wp[((size_t)(b * 512 + dbase + lane)) * 2048 + wpos];
      float diff = pred - mean;
      myacc += diff * diff;
    }
  }
#pragma unroll
  for (int m = 1; m < 8; m <<= 1) myacc += __shfl_xor(myacc, m);
  __shared__ float wacc[4];
  if (lane == 0) wacc[wave] = myacc;
  __syncthreads();
  if (threadIdx.x == 0) {
    float t = (wacc[0] + wacc[1] + wacc[2] + wacc[3]) * (1.0f / 512.0f);
    atomicAdd(W + 3, t);
  }
}

// ------- normalize + transpose + bf16 (A side pre-scaled by log2e/T) -------
__global__ void __launch_bounds__(256) norm_kernel(const float* __restrict__ emb, int L,
                                                   unsigned short* __restrict__ Abf,
                                                   unsigned short* __restrict__ Pbf) {
  __shared__ float tile[128][65];
  __shared__ float np4[4][64];
  __shared__ float scl[64];
  int b = blockIdx.x;
  int l0 = blockIdx.y * 64;
  int tid = threadIdx.x;
  int lx = tid & 63, cq = tid >> 6;
  const float* eb = emb + (size_t)b * 128 * L + l0;
  for (int c = cq; c < 128; c += 4) tile[c][lx] = eb[(size_t)c * L + lx];
  __syncthreads();
  {
    float s = 0.f;
    for (int c = cq; c < 128; c += 4) { float x = tile[c][lx]; s += x * x; }
    np4[cq][lx] = s;
  }
  __syncthreads();
  if (tid < 64) {
    float t = np4[0][tid] + np4[1][tid] + np4[2][tid] + np4[3][tid];
    float nrm = fmaxf(sqrtf(t), 1e-12f);
    scl[tid] = ((tid & 1) ? 1.0f : SA_SCALE) / nrm;  // even l -> anchor (scaled)
  }
  __syncthreads();
  int c = tid & 127, lh = tid >> 7;
  int half = L >> 1;
  for (int lp = lh; lp < 64; lp += 2) {
    int l = l0 + lp;
    int row = b * half + (l >> 1);
    unsigned short v = f2bf(tile[c][lp] * scl[lp]);
    ((l & 1) ? Pbf : Abf)[(size_t)row * 128 + c] = v;
  }
}

// ------- InfoNCE: MFMA bf16, static-max streaming softmax denominator -------
__global__ void __launch_bounds__(512) nce_kernel(const unsigned short* __restrict__ A,
                                                  const unsigned short* __restrict__ P,
                                                  int n, float* __restrict__ acc) {
  int tid = threadIdx.x;
  int wave = tid >> 6, lane = tid & 63;
  int col = lane & 15, quad = lane >> 4;
  int I0 = blockIdx.x * 16;
  const unsigned short* Ap = A + (size_t)(I0 + col) * 128 + quad * 8;
  bf16x8 a0 = *(const bf16x8*)(Ap);
  bf16x8 a1 = *(const bf16x8*)(Ap + 32);
  bf16x8 a2 = *(const bf16x8*)(Ap + 64);
  bf16x8 a3 = *(const bf16x8*)(Ap + 96);
  float rl0 = 0.f, rl1 = 0.f, rl2 = 0.f, rl3 = 0.f;
  float dcap = 0.f;
  int Jq = n >> 3;
  int J0w = wave * Jq, Jend = J0w + Jq;
#pragma unroll 2
  for (int J = J0w; J < Jend; J += 16) {
    const unsigned short* Pp = P + (size_t)(J + col) * 128 + quad * 8;
    bf16x8 b0 = *(const bf16x8*)(Pp);
    bf16x8 b1 = *(const bf16x8*)(Pp + 32);
    bf16x8 b2 = *(const bf16x8*)(Pp + 64);
    bf16x8 b3 = *(const bf16x8*)(Pp + 96);
    f32x4 cfr = {0.f, 0.f, 0.f, 0.f};
    cfr = __builtin_amdgcn_mfma_f32_16x16x32_bf16(a0, b0, cfr, 0, 0, 0);
    cfr = __builtin_amdgcn_mfma_f32_16x16x32_bf16(a1, b1, cfr, 0, 0, 0);
    cfr = __builtin_amdgcn_mfma_f32_16x16x32_bf16(a2, b2, cfr, 0, 0, 0);
    cfr = __builtin_amdgcn_mfma_f32_16x16x32_bf16(a3, b3, cfr, 0, 0, 0);
    rl0 += exp2f(cfr[0] - SA_SCALE);
    rl1 += exp2f(cfr[1] - SA_SCALE);
    rl2 += exp2f(cfr[2] - SA_SCALE);
    rl3 += exp2f(cfr[3] - SA_SCALE);
    if (J == I0) {                        // diagonal tile
      int r = col - (quad << 2);
      if (r == 0) dcap = cfr[0];
      else if (r == 1) dcap = cfr[1];
      else if (r == 2) dcap = cfr[2];
      else if (r == 3) dcap = cfr[3];
    }
  }
  __shared__ float part[8][16][16];
  __shared__ float dpart[8][16];
  __shared__ float rowc[16];
  part[wave][(quad << 2) + 0][col] = rl0;
  part[wave][(quad << 2) + 1][col] = rl1;
  part[wave][(quad << 2) + 2][col] = rl2;
  part[wave][(quad << 2) + 3][col] = rl3;
  if (quad == (col >> 2)) dpart[wave][col] = dcap;
  __syncthreads();
  if (tid < 256) {
    int rrow = tid >> 4, cc = tid & 15;
    float s = 0.f, d = 0.f;
#pragma unroll
    for (int w = 0; w < 8; ++w) { s += part[w][rrow][cc]; d += dpart[w][rrow]; }
#pragma unroll
    for (int m = 1; m < 16; m <<= 1) s += __shfl_xor(s, m);
    if (cc == 0) rowc[rrow] = INV_T + __logf(s) - LN2F * d;
  }
  __syncthreads();
  if (tid == 0) {
    float t = 0.f;
#pragma unroll
    for (int i = 0; i < 16; ++i) t += rowc[i];
    atomicAdd(acc, t);
  }
}

// ---------------- final combine ----------------
__global__ void final_kernel(const float* __restrict__ W, float* __restrict__ out) {
  float n = W[1];
  float charL = (n > 0.f) ? (W[0] / fmaxf(n, 1.f)) : (W[2] / 32768.0f);
  float cnt = W[4];
  float wordL = (cnt > 0.f) ? (W[3] / fmaxf(cnt, 1.f)) : 0.f;
  float phrase = W[5] / 4096.0f;
  float idea = W[6] / 1024.0f;
  out[0] = charL + 0.5f * wordL + 0.1f * phrase + 0.1f * idea;
}

extern "C" void kernel_launch(void* const* d_in, const int* in_sizes, int n_in,
                              void* d_out, int out_size, void* d_ws, size_t ws_size,
                              hipStream_t stream) {
  (void)in_sizes; (void)n_in; (void)out_size; (void)ws_size;
  const float* logits        = (const float*)d_in[0];
  const float* word_preds    = (const float*)d_in[1];
  const float* char_features = (const float*)d_in[2];
  const float* c2            = (const float*)d_in[3];
  const float* c3            = (const float*)d_in[4];
  const int*   targets       = (const int*)d_in[5];
  const float* mask          = (const float*)d_in[6];
  float* out = (float*)d_out;

  char* ws = (char*)d_ws;
  float* W    = (float*)ws;              // W[0..6] accumulators
  int* n_sp   = (int*)(ws + 64);         // 8 ints
  int* sp_pos = (int*)(ws + 128);        // 8*4096 ints, ends at 131200
  unsigned short* A2 = (unsigned short*)(ws + 131200);  // 4096*128 bf16
  unsigned short* P2 = A2 + 4096 * 128;
  unsigned short* A3 = P2 + 4096 * 128;  // 1024*128 bf16
  unsigned short* P3 = A3 + 1024 * 128;  // total ws use ~2.75 MB

  hipMemsetAsync(d_ws, 0, 64, stream);
  scan_kernel<<<8, 256, 0, stream>>>(targets, n_sp, sp_pos);
  ce_kernel<<<1024, 256, 0, stream>>>(logits, targets, mask, W);
  word_kernel<<<dim3(8, 32, 16), 256, 0, stream>>>(word_preds, char_features, n_sp, sp_pos, W);
  norm_kernel<<<dim3(8, 16), 256, 0, stream>>>(c2, 1024, A2, P2);
  norm_kernel<<<dim3(8, 4), 256, 0, stream>>>(c3, 256, A3, P3);
  nce_kernel<<<256, 512, 0, stream>>>(A2, P2, 4096, W + 5);
  nce_kernel<<<64, 512, 0, stream>>>(A3, P3, 1024, W + 6);
  final_kernel<<<1, 1, 0, stream>>>(W, out);
}

// Round 4
// 197.558 us; speedup vs baseline: 2.0583x; 1.5311x over previous
//
#include <hip/hip_runtime.h>

#define SPACE_TOK 63
#define INV_T 14.285714285714286f          /* 1/0.07 */
#define SA_SCALE 20.609929155556595f       /* log2(e)/0.07 ; also the static max bound */
#define LN2F 0.6931471805599453f

typedef __attribute__((ext_vector_type(8))) short bf16x8;
typedef __attribute__((ext_vector_type(4))) float f32x4;

// ---- workspace byte offsets ----
#define O_NSP    0                         /* 8 ints */
#define O_SPPOS  64                        /* 8*4096 ints */
#define O_CECM   131136                    /* 1024 f */
#define O_CEM    135232                    /* 1024 f */
#define O_CEC    139328                    /* 1024 f */
#define O_WPART  143424                    /* 4096 f */
#define O_WCNT   159808                    /* 256 f */
#define O_NP2    160832                    /* 256 f */
#define O_NP3    161856                    /* 64 f */
#define O_A2     162304                    /* bf16 buffers */
#define SZ_A2    (4096*128*2)
#define O_P2     (O_A2 + SZ_A2)
#define O_A3     (O_P2 + SZ_A2)
#define SZ_A3    (1024*128*2)
#define O_P3     (O_A3 + SZ_A3)

__device__ inline unsigned short f2bf(float x) {
  union { float f; unsigned int u; } c; c.f = x;
  unsigned int r = c.u + 0x7fffu + ((c.u >> 16) & 1u);
  return (unsigned short)(r >> 16);
}

// ================= dispatch A: scan(8) | norm2(128) | norm3(32) | ce(1024) =================
__device__ void scan_body(char* smem, const int* __restrict__ targets, char* ws, int b) {
  int tid = threadIdx.x;
  int* toks = (int*)smem;            // 4096 ints
  int* sc   = (int*)(smem + 16384);  // 256 ints
  int* n_sp   = (int*)(ws + O_NSP);
  int* sp_pos = (int*)(ws + O_SPPOS);
  const int4* tb4 = (const int4*)(targets + b * 4096);
#pragma unroll
  for (int i = 0; i < 4; ++i) ((int4*)toks)[tid + 256 * i] = tb4[tid + 256 * i];
  __syncthreads();
  int base = tid * 16;
  int cnt = 0;
#pragma unroll
  for (int i = 0; i < 16; ++i) cnt += (toks[base + i] == SPACE_TOK);
  sc[tid] = cnt;
  __syncthreads();
  for (int off = 1; off < 256; off <<= 1) {
    int v = (tid >= off) ? sc[tid - off] : 0;
    __syncthreads();
    sc[tid] += v;
    __syncthreads();
  }
  int k = sc[tid] - cnt;  // exclusive prefix
  for (int i = 0; i < 16; ++i)
    if (toks[base + i] == SPACE_TOK) sp_pos[b * 4096 + (k++)] = base + i;
  if (tid == 255) n_sp[b] = sc[255];
}

__device__ void norm_body(char* smem, const float* __restrict__ emb, int L,
                          unsigned short* __restrict__ Abf, unsigned short* __restrict__ Pbf,
                          int b, int l0) {
  float (*tile)[65] = (float(*)[65])smem;                 // 128*65*4 = 33280 B
  float (*np4)[64]  = (float(*)[64])(smem + 33280);       // 1024 B
  float* scl        = (float*)(smem + 33280 + 1024);      // 256 B
  int tid = threadIdx.x;
  int lx = tid & 63, cq = tid >> 6;
  const float* eb = emb + (size_t)b * 128 * L + l0;
  for (int c = cq; c < 128; c += 4) tile[c][lx] = eb[(size_t)c * L + lx];
  __syncthreads();
  {
    float s = 0.f;
    for (int c = cq; c < 128; c += 4) { float x = tile[c][lx]; s += x * x; }
    np4[cq][lx] = s;
  }
  __syncthreads();
  if (tid < 64) {
    float t = np4[0][tid] + np4[1][tid] + np4[2][tid] + np4[3][tid];
    float nrm = fmaxf(sqrtf(t), 1e-12f);
    scl[tid] = ((tid & 1) ? 1.0f : SA_SCALE) / nrm;  // even l -> anchor (scaled)
  }
  __syncthreads();
  int c = tid & 127, lh = tid >> 7;
  int half = L >> 1;
  for (int lp = lh; lp < 64; lp += 2) {
    int l = l0 + lp;
    int row = b * half + (l >> 1);
    unsigned short v = f2bf(tile[c][lp] * scl[lp]);
    ((l & 1) ? Pbf : Abf)[(size_t)row * 128 + c] = v;
  }
}

__device__ void ce_body(char* smem, const float* __restrict__ logits,
                        const int* __restrict__ targets, const float* __restrict__ mask,
                        char* ws, int cb) {
  int tid = threadIdx.x;
  int wave = tid >> 6, lane = tid & 63;
  int rbase = cb * 32 + wave * 8;
  float4 v[8];
  float mk[8];
  int tg[8];
#pragma unroll
  for (int rr = 0; rr < 8; ++rr) v[rr] = ((const float4*)logits)[(size_t)(rbase + rr) * 64 + lane];
#pragma unroll
  for (int rr = 0; rr < 8; ++rr) { tg[rr] = targets[rbase + rr]; mk[rr] = mask[rbase + rr]; }
  float aCM = 0.f, aM = 0.f, aC = 0.f;
#pragma unroll
  for (int rr = 0; rr < 8; ++rr) {
    float e = __expf(v[rr].x) + __expf(v[rr].y) + __expf(v[rr].z) + __expf(v[rr].w);
#pragma unroll
    for (int m = 1; m < 64; m <<= 1) e += __shfl_xor(e, m);
    int t = tg[rr];
    int q = t & 3;
    float sel = (q == 0) ? v[rr].x : (q == 1) ? v[rr].y : (q == 2) ? v[rr].z : v[rr].w;
    float xt = __shfl(sel, t >> 2);
    float ce = __logf(e) - xt;
    aCM += ce * mk[rr]; aM += mk[rr]; aC += ce;
  }
  float (*red)[3] = (float(*)[3])smem;
  if (lane == 0) { red[wave][0] = aCM; red[wave][1] = aM; red[wave][2] = aC; }
  __syncthreads();
  if (tid == 0) {
    ((float*)(ws + O_CECM))[cb] = red[0][0] + red[1][0] + red[2][0] + red[3][0];
    ((float*)(ws + O_CEM ))[cb] = red[0][1] + red[1][1] + red[2][1] + red[3][1];
    ((float*)(ws + O_CEC ))[cb] = red[0][2] + red[1][2] + red[2][2] + red[3][2];
  }
}

__global__ void __launch_bounds__(256) fusedA_kernel(const float* __restrict__ logits,
                                                     const int* __restrict__ targets,
                                                     const float* __restrict__ mask,
                                                     const float* __restrict__ c2,
                                                     const float* __restrict__ c3,
                                                     char* __restrict__ ws) {
  extern __shared__ char smem[];
  int bid = blockIdx.x;
  if (bid < 8) {
    scan_body(smem, targets, ws, bid);
  } else if (bid < 136) {
    int nb = bid - 8;
    norm_body(smem, c2, 1024, (unsigned short*)(ws + O_A2), (unsigned short*)(ws + O_P2),
              nb & 7, (nb >> 3) * 64);
  } else if (bid < 168) {
    int nb = bid - 136;
    norm_body(smem, c3, 256, (unsigned short*)(ws + O_A3), (unsigned short*)(ws + O_P3),
              nb & 7, (nb >> 3) * 64);
  } else {
    ce_body(smem, logits, targets, mask, ws, bid - 168);
  }
}

// ================= dispatch B: nce2(256) | nce3(64) | word(4096) =================
__device__ void nce_body(char* smem, const unsigned short* __restrict__ A,
                         const unsigned short* __restrict__ P, int n,
                         float* __restrict__ slot, int blk) {
  int tid = threadIdx.x;
  int wave = tid >> 6, lane = tid & 63;
  int col = lane & 15, quad = lane >> 4;
  int I0 = blk * 16;
  const unsigned short* Ap = A + (size_t)(I0 + col) * 128 + quad * 8;
  bf16x8 a0 = *(const bf16x8*)(Ap);
  bf16x8 a1 = *(const bf16x8*)(Ap + 32);
  bf16x8 a2 = *(const bf16x8*)(Ap + 64);
  bf16x8 a3 = *(const bf16x8*)(Ap + 96);
  float rl0 = 0.f, rl1 = 0.f, rl2 = 0.f, rl3 = 0.f;
  float dcap = 0.f;
  int Jq = n >> 2;                       // 4 waves per block
  int J0w = wave * Jq, Jend = J0w + Jq;
#pragma unroll 2
  for (int J = J0w; J < Jend; J += 16) {
    const unsigned short* Pp = P + (size_t)(J + col) * 128 + quad * 8;
    bf16x8 b0 = *(const bf16x8*)(Pp);
    bf16x8 b1 = *(const bf16x8*)(Pp + 32);
    bf16x8 b2 = *(const bf16x8*)(Pp + 64);
    bf16x8 b3 = *(const bf16x8*)(Pp + 96);
    f32x4 cfr = {0.f, 0.f, 0.f, 0.f};
    cfr = __builtin_amdgcn_mfma_f32_16x16x32_bf16(a0, b0, cfr, 0, 0, 0);
    cfr = __builtin_amdgcn_mfma_f32_16x16x32_bf16(a1, b1, cfr, 0, 0, 0);
    cfr = __builtin_amdgcn_mfma_f32_16x16x32_bf16(a2, b2, cfr, 0, 0, 0);
    cfr = __builtin_amdgcn_mfma_f32_16x16x32_bf16(a3, b3, cfr, 0, 0, 0);
    rl0 += exp2f(cfr[0] - SA_SCALE);
    rl1 += exp2f(cfr[1] - SA_SCALE);
    rl2 += exp2f(cfr[2] - SA_SCALE);
    rl3 += exp2f(cfr[3] - SA_SCALE);
    if (J == I0) {                        // diagonal tile
      int r = col - (quad << 2);
      if (r == 0) dcap = cfr[0];
      else if (r == 1) dcap = cfr[1];
      else if (r == 2) dcap = cfr[2];
      else if (r == 3) dcap = cfr[3];
    }
  }
  float (*part)[16][16] = (float(*)[16][16])smem;          // 4*16*16*4 = 4096 B
  float (*dpart)[16]    = (float(*)[16])(smem + 4096);     // 256 B
  float* rowc           = (float*)(smem + 4096 + 256);     // 64 B
  part[wave][(quad << 2) + 0][col] = rl0;
  part[wave][(quad << 2) + 1][col] = rl1;
  part[wave][(quad << 2) + 2][col] = rl2;
  part[wave][(quad << 2) + 3][col] = rl3;
  if (quad == (col >> 2)) dpart[wave][col] = dcap;
  __syncthreads();
  {
    int rrow = tid >> 4, cc = tid & 15;
    float s = 0.f, d = 0.f;
#pragma unroll
    for (int w = 0; w < 4; ++w) { s += part[w][rrow][cc]; d += dpart[w][rrow]; }
#pragma unroll
    for (int m = 1; m < 16; m <<= 1) s += __shfl_xor(s, m);
    if (cc == 0) rowc[rrow] = INV_T + __logf(s) - LN2F * d;
  }
  __syncthreads();
  if (tid == 0) {
    float t = 0.f;
#pragma unroll
    for (int i = 0; i < 16; ++i) t += rowc[i];
    *slot = t;
  }
}

__device__ void word_body(char* smem, const float* __restrict__ wp,
                          const float* __restrict__ cf, char* ws, int w) {
  int b = w & 7, y = (w >> 3) & 31, z = w >> 8;
  int ns = ((const int*)(ws + O_NSP))[b];
  const int* sp_pos = (const int*)(ws + O_SPPOS);
  int wave = threadIdx.x >> 6, lane = threadIdx.x & 63;
  int dbase = z * 32 + wave * 8;
  float myacc = 0.f;
  float lcnt = 0.f;
  for (int k = 1 + y; k <= ns - 1; k += 32) {
    int t0 = sp_pos[b * 4096 + k - 1];
    int t1 = sp_pos[b * 4096 + k];
    int cnt = t1 - t0 - 1;
    if (cnt <= 0) continue;
    lcnt += 1.0f;                        // uniform across block
    int wpos = t0 >> 1;
    float invc = 1.0f / (float)cnt;
    const float* r0 = cf + ((size_t)(b * 512 + dbase)) * 4096;
    int c0 = (t0 + 1) >> 2;
    int c1 = (t1 + 3) >> 2;
    float s0 = 0.f, s1 = 0.f, s2 = 0.f, s3 = 0.f, s4 = 0.f, s5 = 0.f, s6 = 0.f, s7 = 0.f;
    for (int c = c0 + lane; c < c1; c += 64) {
      int tb = c << 2;
      float4 v0 = *(const float4*)(r0 + 0 * 4096 + tb);
      float4 v1 = *(const float4*)(r0 + 1 * 4096 + tb);
      float4 v2 = *(const float4*)(r0 + 2 * 4096 + tb);
      float4 v3 = *(const float4*)(r0 + 3 * 4096 + tb);
      float4 v4 = *(const float4*)(r0 + 4 * 4096 + tb);
      float4 v5 = *(const float4*)(r0 + 5 * 4096 + tb);
      float4 v6 = *(const float4*)(r0 + 6 * 4096 + tb);
      float4 v7 = *(const float4*)(r0 + 7 * 4096 + tb);
      float m0 = (tb + 0 > t0 && tb + 0 < t1) ? 1.f : 0.f;
      float m1 = (tb + 1 > t0 && tb + 1 < t1) ? 1.f : 0.f;
      float m2 = (tb + 2 > t0 && tb + 2 < t1) ? 1.f : 0.f;
      float m3 = (tb + 3 > t0 && tb + 3 < t1) ? 1.f : 0.f;
      s0 += v0.x * m0 + v0.y * m1 + v0.z * m2 + v0.w * m3;
      s1 += v1.x * m0 + v1.y * m1 + v1.z * m2 + v1.w * m3;
      s2 += v2.x * m0 + v2.y * m1 + v2.z * m2 + v2.w * m3;
      s3 += v3.x * m0 + v3.y * m1 + v3.z * m2 + v3.w * m3;
      s4 += v4.x * m0 + v4.y * m1 + v4.z * m2 + v4.w * m3;
      s5 += v5.x * m0 + v5.y * m1 + v5.z * m2 + v5.w * m3;
      s6 += v6.x * m0 + v6.y * m1 + v6.z * m2 + v6.w * m3;
      s7 += v7.x * m0 + v7.y * m1 + v7.z * m2 + v7.w * m3;
    }
#pragma unroll
    for (int m = 1; m < 64; m <<= 1) {
      s0 += __shfl_xor(s0, m); s1 += __shfl_xor(s1, m);
      s2 += __shfl_xor(s2, m); s3 += __shfl_xor(s3, m);
      s4 += __shfl_xor(s4, m); s5 += __shfl_xor(s5, m);
      s6 += __shfl_xor(s6, m); s7 += __shfl_xor(s7, m);
    }
    if (lane < 8) {
      float sv = (lane == 0) ? s0 : (lane == 1) ? s1 : (lane == 2) ? s2 : (lane == 3) ? s3
               : (lane == 4) ? s4 : (lane == 5) ? s5 : (lane == 6) ? s6 : s7;
      float mean = sv * invc;
      float pred = wp[((size_t)(b * 512 + dbase + lane)) * 2048 + wpos];
      float diff = pred - mean;
      myacc += diff * diff;
    }
  }
#pragma unroll
  for (int m = 1; m < 8; m <<= 1) myacc += __shfl_xor(myacc, m);
  float* wacc = (float*)smem;
  if (lane == 0) wacc[wave] = myacc;
  __syncthreads();
  if (threadIdx.x == 0) {
    ((float*)(ws + O_WPART))[w] = (wacc[0] + wacc[1] + wacc[2] + wacc[3]) * (1.0f / 512.0f);
    if (z == 0) ((float*)(ws + O_WCNT))[w] = lcnt;
  }
}

__global__ void __launch_bounds__(256) fusedB_kernel(const float* __restrict__ wp,
                                                     const float* __restrict__ cf,
                                                     char* __restrict__ ws) {
  extern __shared__ char smem[];
  int bid = blockIdx.x;
  if (bid < 256) {
    nce_body(smem, (const unsigned short*)(ws + O_A2), (const unsigned short*)(ws + O_P2),
             4096, (float*)(ws + O_NP2) + bid, bid);
  } else if (bid < 320) {
    int nb = bid - 256;
    nce_body(smem, (const unsigned short*)(ws + O_A3), (const unsigned short*)(ws + O_P3),
             1024, (float*)(ws + O_NP3) + nb, nb);
  } else {
    word_body(smem, wp, cf, ws, bid - 320);
  }
}

// ================= dispatch C: final tree-reduce + combine =================
__global__ void __launch_bounds__(256) final_kernel(const char* __restrict__ ws,
                                                    float* __restrict__ out) {
  int tid = threadIdx.x;
  int wave = tid >> 6, lane = tid & 63;
  const float* cecm  = (const float*)(ws + O_CECM);
  const float* cem   = (const float*)(ws + O_CEM);
  const float* cec   = (const float*)(ws + O_CEC);
  const float* wpart = (const float*)(ws + O_WPART);
  const float* wcnt  = (const float*)(ws + O_WCNT);
  const float* np2   = (const float*)(ws + O_NP2);
  const float* np3   = (const float*)(ws + O_NP3);
  float v[7] = {0.f, 0.f, 0.f, 0.f, 0.f, 0.f, 0.f};
  for (int i = tid; i < 1024; i += 256) { v[0] += cecm[i]; v[1] += cem[i]; v[2] += cec[i]; }
  for (int i = tid; i < 4096; i += 256) v[3] += wpart[i];
  v[4] = wcnt[tid];
  v[5] = np2[tid];
  if (tid < 64) v[6] = np3[tid];
#pragma unroll
  for (int j = 0; j < 7; ++j) {
    float x = v[j];
#pragma unroll
    for (int m = 1; m < 64; m <<= 1) x += __shfl_xor(x, m);
    v[j] = x;
  }
  __shared__ float fr[4][7];
  if (lane == 0)
#pragma unroll
    for (int j = 0; j < 7; ++j) fr[wave][j] = v[j];
  __syncthreads();
  if (tid == 0) {
    float s[7];
#pragma unroll
    for (int j = 0; j < 7; ++j) s[j] = fr[0][j] + fr[1][j] + fr[2][j] + fr[3][j];
    float n = s[1];
    float charL = (n > 0.f) ? (s[0] / fmaxf(n, 1.f)) : (s[2] / 32768.0f);
    float wordL = (s[4] > 0.f) ? (s[3] / fmaxf(s[4], 1.f)) : 0.f;
    out[0] = charL + 0.5f * wordL + 0.1f * (s[5] / 4096.0f) + 0.1f * (s[6] / 1024.0f);
  }
}

extern "C" void kernel_launch(void* const* d_in, const int* in_sizes, int n_in,
                              void* d_out, int out_size, void* d_ws, size_t ws_size,
                              hipStream_t stream) {
  (void)in_sizes; (void)n_in; (void)out_size; (void)ws_size;
  const float* logits        = (const float*)d_in[0];
  const float* word_preds    = (const float*)d_in[1];
  const float* char_features = (const float*)d_in[2];
  const float* c2            = (const float*)d_in[3];
  const float* c3            = (const float*)d_in[4];
  const int*   targets       = (const int*)d_in[5];
  const float* mask          = (const float*)d_in[6];
  float* out = (float*)d_out;
  char* ws = (char*)d_ws;

  fusedA_kernel<<<1192, 256, 34816, stream>>>(logits, targets, mask, c2, c3, ws);
  fusedB_kernel<<<4416, 256, 4480, stream>>>(word_preds, char_features, ws);
  final_kernel<<<1, 256, 0, stream>>>(ws, out);
}